// Round 3
// baseline (253.132 us; speedup 1.0000x reference)
//
#include <hip/hip_runtime.h>
#include <hip/hip_bf16.h>

// DeformBlock: B=4, C=256, H=W=128, BN=64, K=3.
// All convs via MFMA 16x16x32 bf16 (fp32 accum). Channel-last bf16
// activations; B-fragments pre-packed in ws lane order by k_prep.
//
// R1: k_deform conflict-free b128 phase B.  R3: k_down NaN fix.
// R4: k_up 64-px tiles + contiguous epilogue.  R6: k_deform LDS window.
// R7 FAILED (464us): grid soft-barrier costs ~250us on MI355X. REVERTED.
// R8: split kernels (246us) + window 11x11 (240us).
// R9: fuse k_up INTO k_deform (245us; k_deform_up=70us, 13% HBM, 3 blk/CU).
// R10: drop LDS z-window, gather straight from L2-resident zbf (246us;
//      k_deform_up still 70us but occupancy 59%, VALU 23%, MFMA 3.7% ->
//      stall-bound, not BW/compute-bound).
// R11: attack latency exposure in k_deform_up:
//      (a) prefetch phase-D's x residual (67MB HBM = the critical-path
//          latency) at kernel entry - T14 issue-early/consume-late;
//      (b) phase B 2-way unrolled gather: 8 L2 loads in flight per thread;
//      (c) f32x2 packed bilinear FMA (v_pk_fma_f32) + v_cvt_pk_bf16_f32
//          RNE pack (24 -> 4 inst);
//      (d) remove redundant mid-phase-C barrier;  (e) pipeline k_stats.

typedef __attribute__((ext_vector_type(8))) short bf16x8;   // 8 bf16 = 4 VGPRs
typedef __attribute__((ext_vector_type(4))) short bf16x4;   // 8 B
typedef __attribute__((ext_vector_type(4))) float f32x4;
typedef __attribute__((ext_vector_type(2))) float f32x2;

#define HW   16384
#define CC   256
#define BNC  64

// ws layout (bytes). Total required: ~15.9 MB.
#define WS_STATS   0          // 128 buckets * 512 f32 = 262144
#define WS_SS      262144     // scale[256], shift[256] f32 = 2048
#define WS_FD      264192     // wfrag_down: 4nt*8kk*512 bf16 = 32768
#define WS_FOM     296960     // wfrag_om:   2nt*18kk*512   = 36864
#define WS_FDEF    333824     // wfrag_def:  4nt*18kk*512   = 73728
#define WS_FUP     407552     // wfrag_up:   16nt*2kk*512   = 32768
#define WS_ZBF     440320     // z   [4][16384][64] bf16 = 8388608
#define WS_OM      8828928    // om  [4][16384][27] f32  = 7077888

__device__ __forceinline__ short f2b(float f) {
    unsigned u = __float_as_uint(f);
    unsigned r = (u + 0x7FFFu + ((u >> 16) & 1u)) >> 16;   // RNE
    return (short)r;
}
__device__ __forceinline__ float b2f(short s) {
    return __uint_as_float(((unsigned)(unsigned short)s) << 16);
}

__device__ __forceinline__ void bilin_acc(f32x2 acc[4], int4 d, float w) {
    f32x2 w2 = {w, w};
    int dp[4] = {d.x, d.y, d.z, d.w};
    #pragma unroll
    for (int p = 0; p < 4; ++p) {
        f32x2 v;
        v.x = __uint_as_float((unsigned)dp[p] << 16);
        v.y = __uint_as_float((unsigned)dp[p] & 0xffff0000u);
        acc[p] += w2 * v;                  // v_pk_fma_f32 on CDNA4
    }
}
__device__ __forceinline__ void bilin_store(short* dst, int4 d0, int4 d1,
                                            int4 d2, int4 d3, float4 wt) {
    f32x2 acc[4] = {{0.f,0.f},{0.f,0.f},{0.f,0.f},{0.f,0.f}};
    bilin_acc(acc, d0, wt.x); bilin_acc(acc, d1, wt.y);
    bilin_acc(acc, d2, wt.z); bilin_acc(acc, d3, wt.w);
    unsigned r0, r1, r2, r3;               // RNE pack, 2 f32 -> 1 dword
    asm("v_cvt_pk_bf16_f32 %0, %1, %2" : "=v"(r0) : "v"(acc[0].x), "v"(acc[0].y));
    asm("v_cvt_pk_bf16_f32 %0, %1, %2" : "=v"(r1) : "v"(acc[1].x), "v"(acc[1].y));
    asm("v_cvt_pk_bf16_f32 %0, %1, %2" : "=v"(r2) : "v"(acc[2].x), "v"(acc[2].y));
    asm("v_cvt_pk_bf16_f32 %0, %1, %2" : "=v"(r3) : "v"(acc[3].x), "v"(acc[3].y));
    *(int4*)dst = make_int4((int)r0, (int)r1, (int)r2, (int)r3);
}

// ---------------- prep: pack all weight B-fragments (bf16, lane order) ----
__global__ void k_prep(const float* __restrict__ down_w, const float* __restrict__ off_w,
                       const float* __restrict__ mask_w, const float* __restrict__ def_w,
                       const float* __restrict__ up_w, char* __restrict__ ws) {
    int g = blockIdx.x * 256 + threadIdx.x;
    int row = g >> 6, lane = g & 63;
    if (row >= 172) return;
    int l15 = lane & 15, q = lane >> 4;
    short vals[8];
    short* dst;
    if (row < 32) {                       // down: K=256 over c
        int nt = row >> 3, kk = row & 7;
        int n = nt * 16 + l15;
        for (int j = 0; j < 8; ++j) {
            int c = kk * 32 + q * 8 + j;
            vals[j] = f2b(down_w[n * 256 + c]);
        }
        dst = (short*)(ws + WS_FD) + row * 512 + lane * 8;
    } else if (row < 68) {                // offmask: N=27 (pad 32), K=576, kappa=k*64+c
        int r = row - 32; int nt = r / 18, kk = r % 18;
        int n = nt * 16 + l15;
        for (int j = 0; j < 8; ++j) {
            int kap = kk * 32 + q * 8 + j; int k = kap >> 6, c = kap & 63;
            float v = 0.f;
            if (n < 18)      v = off_w[(n * 64 + c) * 9 + k];
            else if (n < 27) v = mask_w[((n - 18) * 64 + c) * 9 + k];
            vals[j] = f2b(v);
        }
        dst = (short*)(ws + WS_FOM) + r * 512 + lane * 8;
    } else if (row < 140) {               // def: N=64, K=576, u-permutation
        int r = row - 68; int nt = r / 18, kk = r % 18;
        int n = nt * 16 + l15;
        int u = kk * 4 + q, k = u >> 3;
        for (int j = 0; j < 8; ++j) {
            int c = (u & 7) * 8 + j;
            vals[j] = f2b(def_w[(n * 64 + c) * 9 + k]);
        }
        dst = (short*)(ws + WS_FDEF) + r * 512 + lane * 8;
    } else {                              // up: N=256, K=64
        int r = row - 140; int nt = r >> 1, kk = r & 1;
        int o = nt * 16 + l15;
        for (int j = 0; j < 8; ++j) {
            int c = kk * 32 + q * 8 + j;
            vals[j] = f2b(up_w[o * 64 + c]);
        }
        dst = (short*)(ws + WS_FUP) + r * 512 + lane * 8;
    }
    for (int j = 0; j < 8; ++j) dst[j] = vals[j];
}

// ---------------- down: z[b][hw][64] = x[b][c][hw] . W  (bf16 out) --------
__global__ __launch_bounds__(256) void k_down(const float* __restrict__ x,
                                              const short* __restrict__ wfd,
                                              short* __restrict__ zbf) {
    __shared__ __align__(16) short xl[64 * 264];  // [px][c=0..255], stride 264
    int blk = blockIdx.x;                  // 1024 blocks
    int b = blk >> 8;
    int hw0 = (blk & 255) * 64;
    int t = threadIdx.x;
    const float* xb = x + (size_t)b * CC * HW + hw0;
    int px = t & 63, w = t >> 6;
    for (int h = 0; h < 8; ++h) {          // stage ALL 256 channels: 8x b128/thread
        int c0 = h * 32 + w * 8;
        bf16x8 pk;
        #pragma unroll
        for (int j = 0; j < 8; ++j)
            pk[j] = f2b(xb[(size_t)(c0 + j) * HW + px]);
        *(bf16x8*)(&xl[px * 264 + c0]) = pk;   // dest 16B-aligned
    }
    __syncthreads();
    int lane = t & 63, wv = t >> 6;
    int l15 = lane & 15, q = lane >> 4;
    bf16x8 A[8];
    const short* xrow = &xl[(wv * 16 + l15) * 264];
    for (int kk = 0; kk < 8; ++kk)
        A[kk] = *(const bf16x8*)(xrow + kk * 32 + q * 8);
    const bf16x8* Bp = (const bf16x8*)wfd;
    size_t obase = ((size_t)b * HW + hw0 + wv * 16) * 64;
    for (int nt = 0; nt < 4; ++nt) {
        f32x4 acc = {0.f, 0.f, 0.f, 0.f};
        for (int kk = 0; kk < 8; ++kk) {
            bf16x8 Bf = Bp[(nt * 8 + kk) * 64 + lane];
            acc = __builtin_amdgcn_mfma_f32_16x16x32_bf16(A[kk], Bf, acc, 0, 0, 0);
        }
        int n = nt * 16 + l15;
        for (int r = 0; r < 4; ++r) {
            int prow = q * 4 + r;          // D: row=(lane>>4)*4+reg, col=lane&15
            zbf[obase + (size_t)prow * 64 + n] = f2b(acc[r]);
        }
    }
}

// ---------------- offmask: 3x3 conv, 27 outputs, A-frags direct from z ----
__global__ __launch_bounds__(256) void k_offmask(const short* __restrict__ zbf,
                                                 const short* __restrict__ wfom,
                                                 const float* __restrict__ off_b,
                                                 const float* __restrict__ mask_b,
                                                 float* __restrict__ om) {
    int blk = blockIdx.x;                  // 1024 blocks (64-px tiles, row-aligned)
    int b = blk >> 8;
    int hw0 = (blk & 255) * 64;
    int y = hw0 >> 7, x0 = hw0 & 127;
    int t = threadIdx.x, lane = t & 63, wv = t >> 6;
    int l15 = lane & 15, q = lane >> 4;
    int xx0 = x0 + wv * 16 + l15;
    const short* zb = zbf + (size_t)b * HW * 64;
    f32x4 acc0 = {0, 0, 0, 0}, acc1 = {0, 0, 0, 0};
    const bf16x8* Bp = (const bf16x8*)wfom;
    for (int kk = 0; kk < 18; ++kk) {
        int k = kk >> 1;
        int yy = y + (k / 3) - 1;
        int xx = xx0 + (k % 3) - 1;
        int c0 = (kk & 1) * 32 + q * 8;
        bf16x8 A = {0, 0, 0, 0, 0, 0, 0, 0};
        if (yy >= 0 && yy < 128 && xx >= 0 && xx < 128)
            A = *(const bf16x8*)(zb + ((size_t)(yy * 128 + xx)) * 64 + c0);
        bf16x8 B0 = Bp[kk * 64 + lane];
        bf16x8 B1 = Bp[(18 + kk) * 64 + lane];
        acc0 = __builtin_amdgcn_mfma_f32_16x16x32_bf16(A, B0, acc0, 0, 0, 0);
        acc1 = __builtin_amdgcn_mfma_f32_16x16x32_bf16(A, B1, acc1, 0, 0, 0);
    }
    float* omb = om + ((size_t)b * HW + hw0 + wv * 16) * 27;
    for (int half = 0; half < 2; ++half) {
        f32x4 acc = half ? acc1 : acc0;
        int n = half * 16 + l15;
        if (n < 27) {
            for (int r = 0; r < 4; ++r) {
                int prow = q * 4 + r;
                float v = acc[r];
                if (n < 18) v += off_b[n];
                else { v += mask_b[n - 18]; v = 1.f / (1.f + __expf(-v)); }
                omb[prow * 27 + n] = v;
            }
        }
    }
}

// ---------------- deform+up fused: 1x16 px tiles, global-gather ------------
// Phase A: sampling params (global short-offsets; invalid corner => w=0).
// Phase B: 2-way unrolled bilinear gather from zbf (L2) -> valA.  Phase C:
// deform GEMM -> 2KB XOR-swizzled LDS tile.  Phase D: up GEMM -> residual
// (x prefetched at kernel entry) -> NCHW float4 y stores + stats.
__global__ __launch_bounds__(256, 4) void k_deform_up(
        const short* __restrict__ zbf, const float* __restrict__ om,
        const short* __restrict__ wfdef, const float* __restrict__ def_b,
        const short* __restrict__ wfup, const float* __restrict__ x,
        float* __restrict__ yout, float* __restrict__ stats) {
    __shared__ __align__(16) short valA[1152 * 8];     // A-frags, K=576, 18432 B
    __shared__ __align__(16) char  uSm[4608];          // params; z2 tile after B
    int4*   pAi4 = (int4*)uSm;                         // 144 * 16 B
    float4* pAw4 = (float4*)(uSm + 2304);              // 144 * 16 B
    short*  z2t  = (short*)uSm;                        // 16 px x 64 ch bf16 (2 KB)

    int blk = blockIdx.x;                  // 4096 blocks: b * (128 rows * 8 col-tiles)
    int b = blk >> 10;
    int tile = blk & 1023;
    int oy = tile >> 3, xt = (tile & 7) << 4;
    int hw0 = oy * 128 + xt;
    int t = threadIdx.x;
    int lane = t & 63, wv = t >> 6;
    int l15 = lane & 15, q = lane >> 4;
    const short* zbs = zbf + (size_t)b * HW * 64;

    // prefetch x residual (HBM, ~900cy) NOW; consumed in phase D.
    size_t xybase = (size_t)b * CC * HW + hw0 + q * 4;
    float4 xv[4];
    #pragma unroll
    for (int nt = 0; nt < 4; ++nt) {
        int o = (wv * 4 + nt) * 16 + l15;
        xv[nt] = *(const float4*)(x + xybase + (size_t)o * HW);
    }

    if (t < 144) {                         // phase A: sampling params
        int px = t / 9, k = t % 9;
        int ox = xt + px;
        const float* p = om + ((size_t)b * HW + hw0 + px) * 27;
        float dy = p[2 * k], dx = p[2 * k + 1], m = p[18 + k];
        float py  = (float)oy + (float)(k / 3 - 1) + dy;
        float pxf = (float)ox + (float)(k % 3 - 1) + dx;
        float fy = floorf(py), fx = floorf(pxf);
        int iy = (int)fy, ix = (int)fx;
        float wy = py - fy, wx = pxf - fx;
        float ww[4] = { (1.f - wy) * (1.f - wx) * m, (1.f - wy) * wx * m,
                        wy * (1.f - wx) * m,          wy * wx * m };
        int ys[2] = {iy, iy + 1}, xs[2] = {ix, ix + 1};
        int   ri[4]; float rw[4];
        for (int ci = 0; ci < 4; ++ci) {
            int cy = ys[ci >> 1], cx = xs[ci & 1];
            bool v = (cy >= 0 && cy < 128 && cx >= 0 && cx < 128);
            ri[ci] = v ? (cy * 128 + cx) * 64 : 0;  // global short-offset
            rw[ci] = v ? ww[ci] : 0.f;
        }
        pAi4[t] = make_int4(ri[0], ri[1], ri[2], ri[3]);
        pAw4[t] = make_float4(rw[0], rw[1], rw[2], rw[3]);
    }
    __syncthreads();
    // phase B: subtask s = u*16+px, u = kk*4+q; k = u>>3, cg = u&7.
    // 2-way unrolled: pairs (s, s+256) -> 8 gather loads in flight.
    #pragma unroll
    for (int it = 0; it < 2; ++it) {
        int s0 = t + it * 512, s1 = s0 + 256;
        int px0 = s0 & 15, u0 = s0 >> 4;
        int px1 = s1 & 15, u1 = s1 >> 4;
        int4   ia = pAi4[px0 * 9 + (u0 >> 3)];
        float4 wa = pAw4[px0 * 9 + (u0 >> 3)];
        int4   ib = pAi4[px1 * 9 + (u1 >> 3)];
        float4 wb = pAw4[px1 * 9 + (u1 >> 3)];
        int ca = (u0 & 7) * 8, cb = (u1 & 7) * 8;
        int4 da0 = *(const int4*)(zbs + ia.x + ca);
        int4 da1 = *(const int4*)(zbs + ia.y + ca);
        int4 da2 = *(const int4*)(zbs + ia.z + ca);
        int4 da3 = *(const int4*)(zbs + ia.w + ca);
        int4 db0 = *(const int4*)(zbs + ib.x + cb);
        int4 db1 = *(const int4*)(zbs + ib.y + cb);
        int4 db2 = *(const int4*)(zbs + ib.z + cb);
        int4 db3 = *(const int4*)(zbs + ib.w + cb);
        bilin_store(&valA[s0 * 8], da0, da1, da2, da3, wa);
        bilin_store(&valA[s1 * 8], db0, db1, db2, db3, wb);
    }
    if (t < 128) {                         // tail: s = 1024..1151
        int s = 1024 + t;
        int px = s & 15, u = s >> 4;
        int4   ia = pAi4[px * 9 + (u >> 3)];
        float4 wa = pAw4[px * 9 + (u >> 3)];
        int ca = (u & 7) * 8;
        int4 d0 = *(const int4*)(zbs + ia.x + ca);
        int4 d1 = *(const int4*)(zbs + ia.y + ca);
        int4 d2 = *(const int4*)(zbs + ia.z + ca);
        int4 d3 = *(const int4*)(zbs + ia.w + ca);
        bilin_store(&valA[s * 8], d0, d1, d2, d3, wa);
    }
    __syncthreads();
    {   // phase C: deform GEMM, wave = n-tile; result into swizzled LDS tile
        f32x4 acc = {0, 0, 0, 0};
        const bf16x8* Bp = (const bf16x8*)wfdef;
        const bf16x8* Ap = (const bf16x8*)valA;
        for (int kk = 0; kk < 18; ++kk) {
            bf16x8 A  = Ap[kk * 64 + lane];
            bf16x8 Bf = Bp[(wv * 18 + kk) * 64 + lane];
            acc = __builtin_amdgcn_mfma_f32_16x16x32_bf16(A, Bf, acc, 0, 0, 0);
        }
        int n = wv * 16 + l15;
        float bias = def_b[n];
        // post-B barrier already ordered all pA reads before these writes
        for (int r = 0; r < 4; ++r) {
            int prow = q * 4 + r;          // prow = px within the 1x16 row
            z2t[prow * 64 + (n ^ ((prow & 7) << 3))] = f2b(acc[r] + bias);
        }
    }
    __syncthreads();
    // phase D: up GEMM (M=16 px, N=64 o per wave, K=64) + residual + stats
    int rsw = (l15 & 7) << 3;              // XOR swizzle key (16B granules)
    bf16x8 A0 = *(const bf16x8*)&z2t[l15 * 64 + ((q * 8) ^ rsw)];
    bf16x8 A1 = *(const bf16x8*)&z2t[l15 * 64 + ((32 + q * 8) ^ rsw)];
    const bf16x8* Bu = (const bf16x8*)wfup;
    int bucket = blk & 127;
    #pragma unroll
    for (int nt = 0; nt < 4; ++nt) {
        int ont = wv * 4 + nt;             // global o-tile 0..15
        f32x4 acc = {0, 0, 0, 0};
        acc = __builtin_amdgcn_mfma_f32_16x16x32_bf16(A0, Bu[(ont * 2 + 0) * 64 + lane], acc, 0, 0, 0);
        acc = __builtin_amdgcn_mfma_f32_16x16x32_bf16(A1, Bu[(ont * 2 + 1) * 64 + lane], acc, 0, 0, 0);
        int o = ont * 16 + l15;
        size_t pb = xybase + (size_t)o * HW;
        float v0 = acc[0] + xv[nt].x;
        float v1 = acc[1] + xv[nt].y;
        float v2 = acc[2] + xv[nt].z;
        float v3 = acc[3] + xv[nt].w;
        *(float4*)(yout + pb) = make_float4(v0, v1, v2, v3);
        float s  = v0 + v1 + v2 + v3;
        float s2 = v0 * v0 + v1 * v1 + v2 * v2 + v3 * v3;
        s  += __shfl_xor(s, 16);  s  += __shfl_xor(s, 32);
        s2 += __shfl_xor(s2, 16); s2 += __shfl_xor(s2, 32);
        if (q == 0) {
            atomicAdd(&stats[bucket * 512 + o], s);
            atomicAdd(&stats[bucket * 512 + 256 + o], s2);
        }
    }
}

// ---------------- stats reduce -> scale/shift -----------------------------
__global__ void k_stats(const float* __restrict__ stats, const float* __restrict__ gamma,
                        const float* __restrict__ beta, float* __restrict__ ss) {
    int o = threadIdx.x;                   // 256 threads, 1 block
    float a0 = 0.f, a1 = 0.f, a2 = 0.f, a3 = 0.f;
    float b0 = 0.f, b1 = 0.f, b2 = 0.f, b3 = 0.f;
    #pragma unroll 4
    for (int u = 0; u < 128; u += 4) {     // 4 independent chains, pipelined
        a0 += stats[(u + 0) * 512 + o];  b0 += stats[(u + 0) * 512 + 256 + o];
        a1 += stats[(u + 1) * 512 + o];  b1 += stats[(u + 1) * 512 + 256 + o];
        a2 += stats[(u + 2) * 512 + o];  b2 += stats[(u + 2) * 512 + 256 + o];
        a3 += stats[(u + 3) * 512 + o];  b3 += stats[(u + 3) * 512 + 256 + o];
    }
    float s = (a0 + a1) + (a2 + a3);
    float s2 = (b0 + b1) + (b2 + b3);
    float mean = s * (1.f / 65536.f);
    float var  = s2 * (1.f / 65536.f) - mean * mean;
    float rs = rsqrtf(var + 1e-5f);
    float sc = gamma[o] * rs;
    ss[o]       = sc;
    ss[256 + o] = beta[o] - mean * sc;
}

// ---------------- BN apply + SiLU, in-place on d_out ----------------------
__global__ __launch_bounds__(256) void k_bn(float* __restrict__ y, const float* __restrict__ ss) {
    int g = blockIdx.x * 256 + threadIdx.x;            // 1,048,576 threads, 16 floats each
    int o = (g >> 10) & 255;                           // 1024 16-float chunks per plane
    float sc = ss[o], sh = ss[256 + o];
    float4* p = (float4*)y + (size_t)g * 4;
    for (int i = 0; i < 4; ++i) {
        float4 v = p[i];
        float vf[4] = { v.x, v.y, v.z, v.w };
        for (int j = 0; j < 4; ++j) {
            float h = vf[j] * sc + sh;
            vf[j] = h / (1.f + __expf(-h));            // SiLU
        }
        p[i] = make_float4(vf[0], vf[1], vf[2], vf[3]);
    }
}

extern "C" void kernel_launch(void* const* d_in, const int* in_sizes, int n_in,
                              void* d_out, int out_size, void* d_ws, size_t ws_size,
                              hipStream_t stream) {
    const float* x      = (const float*)d_in[0];
    const float* down_w = (const float*)d_in[1];
    const float* off_w  = (const float*)d_in[2];
    const float* off_b  = (const float*)d_in[3];
    const float* mask_w = (const float*)d_in[4];
    const float* mask_b = (const float*)d_in[5];
    const float* def_w  = (const float*)d_in[6];
    const float* def_b  = (const float*)d_in[7];
    const float* up_w   = (const float*)d_in[8];
    const float* gamma  = (const float*)d_in[9];
    const float* beta   = (const float*)d_in[10];
    char* ws = (char*)d_ws;
    float* stats = (float*)(ws + WS_STATS);
    float* ss    = (float*)(ws + WS_SS);
    short* wfd   = (short*)(ws + WS_FD);
    short* wfom  = (short*)(ws + WS_FOM);
    short* wfdef = (short*)(ws + WS_FDEF);
    short* wfup  = (short*)(ws + WS_FUP);
    short* zbf   = (short*)(ws + WS_ZBF);
    float* om    = (float*)(ws + WS_OM);
    float* y     = (float*)d_out;

    hipMemsetAsync(stats, 0, 128 * 512 * sizeof(float), stream);
    hipLaunchKernelGGL(k_prep,      dim3(43),   dim3(256), 0, stream, down_w, off_w, mask_w, def_w, up_w, ws);
    hipLaunchKernelGGL(k_down,      dim3(1024), dim3(256), 0, stream, x, wfd, zbf);
    hipLaunchKernelGGL(k_offmask,   dim3(1024), dim3(256), 0, stream, zbf, wfom, off_b, mask_b, om);
    hipLaunchKernelGGL(k_deform_up, dim3(4096), dim3(256), 0, stream, zbf, om, wfdef, def_b, wfup, x, y, stats);
    hipLaunchKernelGGL(k_stats,     dim3(1),    dim3(256), 0, stream, stats, gamma, beta, ss);
    hipLaunchKernelGGL(k_bn,        dim3(4096), dim3(256), 0, stream, y, ss);
}

// Round 4
// 230.149 us; speedup vs baseline: 1.0999x; 1.0999x over previous
//
#include <hip/hip_runtime.h>
#include <hip/hip_bf16.h>

// DeformBlock: B=4, C=256, H=W=128, BN=64, K=3.
// All convs via MFMA 16x16x32 bf16 (fp32 accum). Channel-last bf16
// activations; B-fragments pre-packed in ws lane order by k_prep.
//
// R1: k_deform conflict-free b128 phase B.  R3: k_down NaN fix.
// R4: k_up 64-px tiles + contiguous epilogue.  R6: k_deform LDS window.
// R7 FAILED (464us): grid soft-barrier ~250us on MI355X. REVERTED.
// R8: split kernels (246us) + window 11x11 (240us).
// R9: fuse k_up INTO k_deform (245us; k_deform_up=70us, 3 blk/CU).
// R10: drop LDS z-window, gather from L2-resident zbf (246us; still 70us,
//      occupancy 59%, VALU 23%, MFMA 3.7% -> stall-bound).
// R11 FAILED (253us): prefetch/unroll/pk-fma all neutral-to-negative ->
//      NOT latency-bound. REVERTED.
// R12: phase B gather was TRANSACTION-bound: old mapping (s&15=px) made 64
//      lanes hit 64 distinct lines with 16B each (4608 line-transactions
//      per block ~ 30us/CU). New mapping s = px*72 + k*8 + cg: 8
//      consecutive lanes share (px,k,corner), differ in cg -> each corner
//      octet reads one contiguous 128B line (~8x fewer transactions).
//      valA writes (stride-256B) go through bijective XOR swizzle
//      unit = u*16 + (px ^ (u&15)); phase C reads with same swizzle.

typedef __attribute__((ext_vector_type(8))) short bf16x8;   // 8 bf16 = 4 VGPRs
typedef __attribute__((ext_vector_type(4))) short bf16x4;   // 8 B
typedef __attribute__((ext_vector_type(4))) float f32x4;

#define HW   16384
#define CC   256
#define BNC  64

// ws layout (bytes). Total required: ~15.9 MB.
#define WS_STATS   0          // 128 buckets * 512 f32 = 262144
#define WS_SS      262144     // scale[256], shift[256] f32 = 2048
#define WS_FD      264192     // wfrag_down: 4nt*8kk*512 bf16 = 32768
#define WS_FOM     296960     // wfrag_om:   2nt*18kk*512   = 36864
#define WS_FDEF    333824     // wfrag_def:  4nt*18kk*512   = 73728
#define WS_FUP     407552     // wfrag_up:   16nt*2kk*512   = 32768
#define WS_ZBF     440320     // z   [4][16384][64] bf16 = 8388608
#define WS_OM      8828928    // om  [4][16384][27] f32  = 7077888

__device__ __forceinline__ short f2b(float f) {
    unsigned u = __float_as_uint(f);
    unsigned r = (u + 0x7FFFu + ((u >> 16) & 1u)) >> 16;   // RNE
    return (short)r;
}
__device__ __forceinline__ float b2f(short s) {
    return __uint_as_float(((unsigned)(unsigned short)s) << 16);
}

// ---------------- prep: pack all weight B-fragments (bf16, lane order) ----
__global__ void k_prep(const float* __restrict__ down_w, const float* __restrict__ off_w,
                       const float* __restrict__ mask_w, const float* __restrict__ def_w,
                       const float* __restrict__ up_w, char* __restrict__ ws) {
    int g = blockIdx.x * 256 + threadIdx.x;
    int row = g >> 6, lane = g & 63;
    if (row >= 172) return;
    int l15 = lane & 15, q = lane >> 4;
    short vals[8];
    short* dst;
    if (row < 32) {                       // down: K=256 over c
        int nt = row >> 3, kk = row & 7;
        int n = nt * 16 + l15;
        for (int j = 0; j < 8; ++j) {
            int c = kk * 32 + q * 8 + j;
            vals[j] = f2b(down_w[n * 256 + c]);
        }
        dst = (short*)(ws + WS_FD) + row * 512 + lane * 8;
    } else if (row < 68) {                // offmask: N=27 (pad 32), K=576, kappa=k*64+c
        int r = row - 32; int nt = r / 18, kk = r % 18;
        int n = nt * 16 + l15;
        for (int j = 0; j < 8; ++j) {
            int kap = kk * 32 + q * 8 + j; int k = kap >> 6, c = kap & 63;
            float v = 0.f;
            if (n < 18)      v = off_w[(n * 64 + c) * 9 + k];
            else if (n < 27) v = mask_w[((n - 18) * 64 + c) * 9 + k];
            vals[j] = f2b(v);
        }
        dst = (short*)(ws + WS_FOM) + r * 512 + lane * 8;
    } else if (row < 140) {               // def: N=64, K=576, u-permutation
        int r = row - 68; int nt = r / 18, kk = r % 18;
        int n = nt * 16 + l15;
        int u = kk * 4 + q, k = u >> 3;
        for (int j = 0; j < 8; ++j) {
            int c = (u & 7) * 8 + j;
            vals[j] = f2b(def_w[(n * 64 + c) * 9 + k]);
        }
        dst = (short*)(ws + WS_FDEF) + r * 512 + lane * 8;
    } else {                              // up: N=256, K=64
        int r = row - 140; int nt = r >> 1, kk = r & 1;
        int o = nt * 16 + l15;
        for (int j = 0; j < 8; ++j) {
            int c = kk * 32 + q * 8 + j;
            vals[j] = f2b(up_w[o * 64 + c]);
        }
        dst = (short*)(ws + WS_FUP) + r * 512 + lane * 8;
    }
    for (int j = 0; j < 8; ++j) dst[j] = vals[j];
}

// ---------------- down: z[b][hw][64] = x[b][c][hw] . W  (bf16 out) --------
__global__ __launch_bounds__(256) void k_down(const float* __restrict__ x,
                                              const short* __restrict__ wfd,
                                              short* __restrict__ zbf) {
    __shared__ __align__(16) short xl[64 * 264];  // [px][c=0..255], stride 264
    int blk = blockIdx.x;                  // 1024 blocks
    int b = blk >> 8;
    int hw0 = (blk & 255) * 64;
    int t = threadIdx.x;
    const float* xb = x + (size_t)b * CC * HW + hw0;
    int px = t & 63, w = t >> 6;
    for (int h = 0; h < 8; ++h) {          // stage ALL 256 channels: 8x b128/thread
        int c0 = h * 32 + w * 8;
        bf16x8 pk;
        #pragma unroll
        for (int j = 0; j < 8; ++j)
            pk[j] = f2b(xb[(size_t)(c0 + j) * HW + px]);
        *(bf16x8*)(&xl[px * 264 + c0]) = pk;   // dest 16B-aligned
    }
    __syncthreads();
    int lane = t & 63, wv = t >> 6;
    int l15 = lane & 15, q = lane >> 4;
    bf16x8 A[8];
    const short* xrow = &xl[(wv * 16 + l15) * 264];
    for (int kk = 0; kk < 8; ++kk)
        A[kk] = *(const bf16x8*)(xrow + kk * 32 + q * 8);
    const bf16x8* Bp = (const bf16x8*)wfd;
    size_t obase = ((size_t)b * HW + hw0 + wv * 16) * 64;
    for (int nt = 0; nt < 4; ++nt) {
        f32x4 acc = {0.f, 0.f, 0.f, 0.f};
        for (int kk = 0; kk < 8; ++kk) {
            bf16x8 Bf = Bp[(nt * 8 + kk) * 64 + lane];
            acc = __builtin_amdgcn_mfma_f32_16x16x32_bf16(A[kk], Bf, acc, 0, 0, 0);
        }
        int n = nt * 16 + l15;
        for (int r = 0; r < 4; ++r) {
            int prow = q * 4 + r;          // D: row=(lane>>4)*4+reg, col=lane&15
            zbf[obase + (size_t)prow * 64 + n] = f2b(acc[r]);
        }
    }
}

// ---------------- offmask: 3x3 conv, 27 outputs, A-frags direct from z ----
__global__ __launch_bounds__(256) void k_offmask(const short* __restrict__ zbf,
                                                 const short* __restrict__ wfom,
                                                 const float* __restrict__ off_b,
                                                 const float* __restrict__ mask_b,
                                                 float* __restrict__ om) {
    int blk = blockIdx.x;                  // 1024 blocks (64-px tiles, row-aligned)
    int b = blk >> 8;
    int hw0 = (blk & 255) * 64;
    int y = hw0 >> 7, x0 = hw0 & 127;
    int t = threadIdx.x, lane = t & 63, wv = t >> 6;
    int l15 = lane & 15, q = lane >> 4;
    int xx0 = x0 + wv * 16 + l15;
    const short* zb = zbf + (size_t)b * HW * 64;
    f32x4 acc0 = {0, 0, 0, 0}, acc1 = {0, 0, 0, 0};
    const bf16x8* Bp = (const bf16x8*)wfom;
    for (int kk = 0; kk < 18; ++kk) {
        int k = kk >> 1;
        int yy = y + (k / 3) - 1;
        int xx = xx0 + (k % 3) - 1;
        int c0 = (kk & 1) * 32 + q * 8;
        bf16x8 A = {0, 0, 0, 0, 0, 0, 0, 0};
        if (yy >= 0 && yy < 128 && xx >= 0 && xx < 128)
            A = *(const bf16x8*)(zb + ((size_t)(yy * 128 + xx)) * 64 + c0);
        bf16x8 B0 = Bp[kk * 64 + lane];
        bf16x8 B1 = Bp[(18 + kk) * 64 + lane];
        acc0 = __builtin_amdgcn_mfma_f32_16x16x32_bf16(A, B0, acc0, 0, 0, 0);
        acc1 = __builtin_amdgcn_mfma_f32_16x16x32_bf16(A, B1, acc1, 0, 0, 0);
    }
    float* omb = om + ((size_t)b * HW + hw0 + wv * 16) * 27;
    for (int half = 0; half < 2; ++half) {
        f32x4 acc = half ? acc1 : acc0;
        int n = half * 16 + l15;
        if (n < 27) {
            for (int r = 0; r < 4; ++r) {
                int prow = q * 4 + r;
                float v = acc[r];
                if (n < 18) v += off_b[n];
                else { v += mask_b[n - 18]; v = 1.f / (1.f + __expf(-v)); }
                omb[prow * 27 + n] = v;
            }
        }
    }
}

// ---------------- deform+up fused: 1x16 px tiles, coalesced gather --------
// Phase A: sampling params (global short-offsets; invalid corner => w=0).
// Phase B: bilinear gather, s = px*72 + k*8 + cg so 8 consecutive lanes
// read one contiguous 128B corner row; valA XOR-swizzled.  Phase C: deform
// GEMM (swizzled A reads) -> 2KB XOR-swizzled z2 tile.  Phase D: up GEMM
// -> residual add -> NCHW float4 y stores (full 64B lines) + stats.
__global__ __launch_bounds__(256) void k_deform_up(
        const short* __restrict__ zbf, const float* __restrict__ om,
        const short* __restrict__ wfdef, const float* __restrict__ def_b,
        const short* __restrict__ wfup, const float* __restrict__ x,
        float* __restrict__ yout, float* __restrict__ stats) {
    __shared__ __align__(16) short valA[1152 * 8];     // A-frags, K=576, 18432 B
    __shared__ __align__(16) char  uSm[4608];          // params; z2 tile after B
    int4*   pAi4 = (int4*)uSm;                         // 144 * 16 B
    float4* pAw4 = (float4*)(uSm + 2304);              // 144 * 16 B
    short*  z2t  = (short*)uSm;                        // 16 px x 64 ch bf16 (2 KB)

    int blk = blockIdx.x;                  // 4096 blocks: b * (128 rows * 8 col-tiles)
    int b = blk >> 10;
    int tile = blk & 1023;
    int oy = tile >> 3, xt = (tile & 7) << 4;
    int hw0 = oy * 128 + xt;
    int t = threadIdx.x;
    const short* zbs = zbf + (size_t)b * HW * 64;
    if (t < 144) {                         // phase A: sampling params
        int px = t / 9, k = t % 9;
        int ox = xt + px;
        const float* p = om + ((size_t)b * HW + hw0 + px) * 27;
        float dy = p[2 * k], dx = p[2 * k + 1], m = p[18 + k];
        float py  = (float)oy + (float)(k / 3 - 1) + dy;
        float pxf = (float)ox + (float)(k % 3 - 1) + dx;
        float fy = floorf(py), fx = floorf(pxf);
        int iy = (int)fy, ix = (int)fx;
        float wy = py - fy, wx = pxf - fx;
        float ww[4] = { (1.f - wy) * (1.f - wx) * m, (1.f - wy) * wx * m,
                        wy * (1.f - wx) * m,          wy * wx * m };
        int ys[2] = {iy, iy + 1}, xs[2] = {ix, ix + 1};
        int   ri[4]; float rw[4];
        for (int ci = 0; ci < 4; ++ci) {
            int cy = ys[ci >> 1], cx = xs[ci & 1];
            bool v = (cy >= 0 && cy < 128 && cx >= 0 && cx < 128);
            ri[ci] = v ? (cy * 128 + cx) * 64 : 0;  // global short-offset
            rw[ci] = v ? ww[ci] : 0.f;
        }
        pAi4[t] = make_int4(ri[0], ri[1], ri[2], ri[3]);
        pAw4[t] = make_float4(rw[0], rw[1], rw[2], rw[3]);
    }
    __syncthreads();
    // phase B: s = px*72 + u, u = k*8 + cg.  8-lane octets (aligned: 72px
    // and 256 are both 0 mod 8) share (px,k,corner) and differ in cg ->
    // each corner octet-load is one contiguous 128B line.
    for (int it = 0; it < 5; ++it) {
        int s = t + it * 256;
        if (s < 1152) {
            int px = s / 72;               // 0..15 (magic-mul)
            int u  = s - px * 72;          // 0..71
            int k = u >> 3, cg = u & 7;
            int task = px * 9 + k;
            int4   idx = pAi4[task];
            float4 wt  = pAw4[task];
            int   ii[4] = { idx.x, idx.y, idx.z, idx.w };
            float wwt[4] = { wt.x, wt.y, wt.z, wt.w };
            int cgs = cg * 8;
            float acc[8] = {0.f, 0.f, 0.f, 0.f, 0.f, 0.f, 0.f, 0.f};
            #pragma unroll
            for (int ci = 0; ci < 4; ++ci) {
                float w = wwt[ci];
                int4 d = *(const int4*)(zbs + ii[ci] + cgs);
                int dp[4] = { d.x, d.y, d.z, d.w };
                #pragma unroll
                for (int p = 0; p < 4; ++p) {
                    float lo = __uint_as_float((unsigned)dp[p] << 16);
                    float hi = __uint_as_float((unsigned)dp[p] & 0xffff0000u);
                    acc[2 * p]     += w * lo;
                    acc[2 * p + 1] += w * hi;
                }
            }
            bf16x8 out;
            #pragma unroll
            for (int j = 0; j < 8; ++j) out[j] = f2b(acc[j]);
            int unit = u * 16 + (px ^ (u & 15));   // bijective XOR swizzle
            *(bf16x8*)(&valA[unit * 8]) = out;     // conflict-free b128
        }
    }
    __syncthreads();
    int lane = t & 63, wv = t >> 6;
    int l15 = lane & 15, q = lane >> 4;
    {   // phase C: deform GEMM, wave = n-tile; result into swizzled LDS tile
        f32x4 acc = {0, 0, 0, 0};
        const bf16x8* Bp = (const bf16x8*)wfdef;
        for (int kk = 0; kk < 18; ++kk) {
            int u = kk * 4 + q;
            int unit = u * 16 + (l15 ^ (u & 15));  // matches phase-B swizzle
            bf16x8 A  = *(const bf16x8*)(&valA[unit * 8]);
            bf16x8 Bf = Bp[(wv * 18 + kk) * 64 + lane];
            acc = __builtin_amdgcn_mfma_f32_16x16x32_bf16(A, Bf, acc, 0, 0, 0);
        }
        int n = wv * 16 + l15;
        float bias = def_b[n];
        // post-B barrier already ordered all pA reads before these writes
        for (int r = 0; r < 4; ++r) {
            int prow = q * 4 + r;          // prow = px within the 1x16 row
            z2t[prow * 64 + (n ^ ((prow & 7) << 3))] = f2b(acc[r] + bias);
        }
    }
    __syncthreads();
    // phase D: up GEMM (M=16 px, N=64 o per wave, K=64) + residual + stats
    int rsw = (l15 & 7) << 3;              // XOR swizzle key (16B granules)
    bf16x8 A0 = *(const bf16x8*)&z2t[l15 * 64 + ((q * 8) ^ rsw)];
    bf16x8 A1 = *(const bf16x8*)&z2t[l15 * 64 + ((32 + q * 8) ^ rsw)];
    const bf16x8* Bu = (const bf16x8*)wfup;
    int bucket = blk & 127;
    size_t xybase = (size_t)b * CC * HW + hw0 + q * 4;
    #pragma unroll
    for (int nt = 0; nt < 4; ++nt) {
        int ont = wv * 4 + nt;             // global o-tile 0..15
        f32x4 acc = {0, 0, 0, 0};
        acc = __builtin_amdgcn_mfma_f32_16x16x32_bf16(A0, Bu[(ont * 2 + 0) * 64 + lane], acc, 0, 0, 0);
        acc = __builtin_amdgcn_mfma_f32_16x16x32_bf16(A1, Bu[(ont * 2 + 1) * 64 + lane], acc, 0, 0, 0);
        int o = ont * 16 + l15;
        size_t pb = xybase + (size_t)o * HW;
        float4 xv = *(const float4*)(x + pb);      // rows q*4..q*4+3 = acc[0..3]
        float v0 = acc[0] + xv.x;
        float v1 = acc[1] + xv.y;
        float v2 = acc[2] + xv.z;
        float v3 = acc[3] + xv.w;
        *(float4*)(yout + pb) = make_float4(v0, v1, v2, v3);
        float s  = v0 + v1 + v2 + v3;
        float s2 = v0 * v0 + v1 * v1 + v2 * v2 + v3 * v3;
        s  += __shfl_xor(s, 16);  s  += __shfl_xor(s, 32);
        s2 += __shfl_xor(s2, 16); s2 += __shfl_xor(s2, 32);
        if (q == 0) {
            atomicAdd(&stats[bucket * 512 + o], s);
            atomicAdd(&stats[bucket * 512 + 256 + o], s2);
        }
    }
}

// ---------------- stats reduce -> scale/shift -----------------------------
__global__ void k_stats(const float* __restrict__ stats, const float* __restrict__ gamma,
                        const float* __restrict__ beta, float* __restrict__ ss) {
    int o = threadIdx.x;                   // 256 threads, 1 block
    float a0 = 0.f, a1 = 0.f, a2 = 0.f, a3 = 0.f;
    float b0 = 0.f, b1 = 0.f, b2 = 0.f, b3 = 0.f;
    #pragma unroll 4
    for (int u = 0; u < 128; u += 4) {     // 4 independent chains, pipelined
        a0 += stats[(u + 0) * 512 + o];  b0 += stats[(u + 0) * 512 + 256 + o];
        a1 += stats[(u + 1) * 512 + o];  b1 += stats[(u + 1) * 512 + 256 + o];
        a2 += stats[(u + 2) * 512 + o];  b2 += stats[(u + 2) * 512 + 256 + o];
        a3 += stats[(u + 3) * 512 + o];  b3 += stats[(u + 3) * 512 + 256 + o];
    }
    float s = (a0 + a1) + (a2 + a3);
    float s2 = (b0 + b1) + (b2 + b3);
    float mean = s * (1.f / 65536.f);
    float var  = s2 * (1.f / 65536.f) - mean * mean;
    float rs = rsqrtf(var + 1e-5f);
    float sc = gamma[o] * rs;
    ss[o]       = sc;
    ss[256 + o] = beta[o] - mean * sc;
}

// ---------------- BN apply + SiLU, in-place on d_out ----------------------
__global__ __launch_bounds__(256) void k_bn(float* __restrict__ y, const float* __restrict__ ss) {
    int g = blockIdx.x * 256 + threadIdx.x;            // 1,048,576 threads, 16 floats each
    int o = (g >> 10) & 255;                           // 1024 16-float chunks per plane
    float sc = ss[o], sh = ss[256 + o];
    float4* p = (float4*)y + (size_t)g * 4;
    for (int i = 0; i < 4; ++i) {
        float4 v = p[i];
        float vf[4] = { v.x, v.y, v.z, v.w };
        for (int j = 0; j < 4; ++j) {
            float h = vf[j] * sc + sh;
            vf[j] = h / (1.f + __expf(-h));            // SiLU
        }
        p[i] = make_float4(vf[0], vf[1], vf[2], vf[3]);
    }
}

extern "C" void kernel_launch(void* const* d_in, const int* in_sizes, int n_in,
                              void* d_out, int out_size, void* d_ws, size_t ws_size,
                              hipStream_t stream) {
    const float* x      = (const float*)d_in[0];
    const float* down_w = (const float*)d_in[1];
    const float* off_w  = (const float*)d_in[2];
    const float* off_b  = (const float*)d_in[3];
    const float* mask_w = (const float*)d_in[4];
    const float* mask_b = (const float*)d_in[5];
    const float* def_w  = (const float*)d_in[6];
    const float* def_b  = (const float*)d_in[7];
    const float* up_w   = (const float*)d_in[8];
    const float* gamma  = (const float*)d_in[9];
    const float* beta   = (const float*)d_in[10];
    char* ws = (char*)d_ws;
    float* stats = (float*)(ws + WS_STATS);
    float* ss    = (float*)(ws + WS_SS);
    short* wfd   = (short*)(ws + WS_FD);
    short* wfom  = (short*)(ws + WS_FOM);
    short* wfdef = (short*)(ws + WS_FDEF);
    short* wfup  = (short*)(ws + WS_FUP);
    short* zbf   = (short*)(ws + WS_ZBF);
    float* om    = (float*)(ws + WS_OM);
    float* y     = (float*)d_out;

    hipMemsetAsync(stats, 0, 128 * 512 * sizeof(float), stream);
    hipLaunchKernelGGL(k_prep,      dim3(43),   dim3(256), 0, stream, down_w, off_w, mask_w, def_w, up_w, ws);
    hipLaunchKernelGGL(k_down,      dim3(1024), dim3(256), 0, stream, x, wfd, zbf);
    hipLaunchKernelGGL(k_offmask,   dim3(1024), dim3(256), 0, stream, zbf, wfom, off_b, mask_b, om);
    hipLaunchKernelGGL(k_deform_up, dim3(4096), dim3(256), 0, stream, zbf, om, wfdef, def_b, wfup, x, y, stats);
    hipLaunchKernelGGL(k_stats,     dim3(1),    dim3(256), 0, stream, stats, gamma, beta, ss);
    hipLaunchKernelGGL(k_bn,        dim3(4096), dim3(256), 0, stream, y, ss);
}